// Round 1
// baseline (1948.253 us; speedup 1.0000x reference)
//
#include <hip/hip_runtime.h>
#include <stdint.h>

#define NN 50000
#define NE 800000
#define NG 64
#define CH 128
#define CO 16

// ---------------- graph preprocessing ----------------

__global__ void k_hist(const int* __restrict__ src, const int* __restrict__ dst,
                       int* __restrict__ deg, int* __restrict__ hist, int E) {
  int e = blockIdx.x * blockDim.x + threadIdx.x;
  if (e < E) {
    atomicAdd(&deg[src[e]], 1);
    atomicAdd(&hist[dst[e]], 1);
  }
}

// exclusive scan of hist[0..n) into row_ptr[0..n], single block of 1024
__global__ void k_scan(const int* __restrict__ hist, int* __restrict__ row_ptr, int n) {
  __shared__ int sm[1024];
  __shared__ int carry;
  if (threadIdx.x == 0) { carry = 0; row_ptr[0] = 0; }
  __syncthreads();
  for (int base = 0; base < n; base += 1024) {
    int i = base + threadIdx.x;
    int v = (i < n) ? hist[i] : 0;
    sm[threadIdx.x] = v;
    __syncthreads();
    for (int off = 1; off < 1024; off <<= 1) {
      int t = (threadIdx.x >= off) ? sm[threadIdx.x - off] : 0;
      __syncthreads();
      sm[threadIdx.x] += t;
      __syncthreads();
    }
    int c = carry;
    if (i < n) row_ptr[i + 1] = c + sm[threadIdx.x];
    __syncthreads();
    if (threadIdx.x == 1023) carry = c + sm[1023];
    __syncthreads();
  }
}

__global__ void k_scatter(const int* __restrict__ src, const int* __restrict__ dst,
                          const int* __restrict__ deg, const int* __restrict__ row_ptr,
                          int* __restrict__ fill, int* __restrict__ ssrc,
                          float* __restrict__ sw, int E) {
  int e = blockIdx.x * blockDim.x + threadIdx.x;
  if (e < E) {
    int s = src[e], d = dst[e];
    int ds = deg[s], dd = deg[d];
    float di = ds > 0 ? rsqrtf((float)ds) : 0.f;
    float dj = dd > 0 ? rsqrtf((float)dd) : 0.f;
    float w = -di * dj;
    int pos = row_ptr[d] + atomicAdd(&fill[d], 1);
    ssrc[pos] = s;
    sw[pos]  = w;
  }
}

// ---------------- propagation: out[i] = sum_{e: dst=i} w_e * h[src_e]  (optionally 2*p - tx0)

__global__ __launch_bounds__(256) void k_prop(
    const float* __restrict__ hin, const float* __restrict__ tx0,
    float* __restrict__ hout, const int* __restrict__ row_ptr,
    const int* __restrict__ ssrc, const float* __restrict__ sw, int n) {
  int wave = threadIdx.x >> 6;
  int lane = threadIdx.x & 63;
  int node = blockIdx.x * (blockDim.x >> 6) + wave;
  if (node >= n) return;
  int beg = row_ptr[node], end = row_ptr[node + 1];
  float ax = 0.f, ay = 0.f;
  int co = lane * 2;
  for (int e = beg; e < end; ++e) {
    int s = ssrc[e];
    float w = sw[e];
    const float2 v = *reinterpret_cast<const float2*>(hin + (size_t)s * CH + co);
    ax = fmaf(w, v.x, ax);
    ay = fmaf(w, v.y, ay);
  }
  size_t o = (size_t)node * CH + co;
  if (tx0) {
    ax = 2.f * ax - tx0[o];
    ay = 2.f * ay - tx0[o + 1];
  }
  float2 r; r.x = ax; r.y = ay;
  *reinterpret_cast<float2*>(hout + o) = r;
}

// ---------------- GEMM: out[n x 128] (+)= in[n x 128] @ W[128 x 128] (one k-slice)

__global__ __launch_bounds__(256) void k_gemm128(
    const float* __restrict__ in, const float* __restrict__ W,
    const float* __restrict__ bias, float* __restrict__ out,
    int n, int accum, int dorelu) {
  __shared__ float As[64 * 132];
  __shared__ float Ws[128 * 64];
  int t = threadIdx.x;
  int row0 = blockIdx.x * 64;
  int col0 = blockIdx.y * 64;

  // stage W tile 128 x 64 (row-major, contiguous cols)
  for (int i = t; i < 128 * 16; i += 256) {   // float4 index
    int c = i >> 4;
    int j4 = i & 15;
    *reinterpret_cast<float4*>(&Ws[c * 64 + j4 * 4]) =
        *reinterpret_cast<const float4*>(&W[c * 128 + col0 + j4 * 4]);
  }
  // stage A tile 64 x 128 (padded stride 132)
  for (int i = t; i < 64 * 32; i += 256) {    // float4 index
    int r = i >> 5;
    int c4 = i & 31;
    int grow = row0 + r;
    float4 a;
    if (grow < n) a = *reinterpret_cast<const float4*>(&in[(size_t)grow * CH + c4 * 4]);
    else { a.x = a.y = a.z = a.w = 0.f; }
    *reinterpret_cast<float4*>(&As[r * 132 + c4 * 4]) = a;
  }
  __syncthreads();

  int tx = t & 7;    // 8 col groups of 8
  int ty = t >> 3;   // 32 row groups of 2
  float acc[2][8];
#pragma unroll
  for (int r = 0; r < 2; ++r)
#pragma unroll
    for (int j = 0; j < 8; ++j) acc[r][j] = 0.f;

#pragma unroll 4
  for (int c = 0; c < 128; ++c) {
    float a0 = As[(ty * 2 + 0) * 132 + c];
    float a1 = As[(ty * 2 + 1) * 132 + c];
    const float4 w0 = *reinterpret_cast<const float4*>(&Ws[c * 64 + tx * 8]);
    const float4 w1 = *reinterpret_cast<const float4*>(&Ws[c * 64 + tx * 8 + 4]);
    acc[0][0] = fmaf(a0, w0.x, acc[0][0]);
    acc[0][1] = fmaf(a0, w0.y, acc[0][1]);
    acc[0][2] = fmaf(a0, w0.z, acc[0][2]);
    acc[0][3] = fmaf(a0, w0.w, acc[0][3]);
    acc[0][4] = fmaf(a0, w1.x, acc[0][4]);
    acc[0][5] = fmaf(a0, w1.y, acc[0][5]);
    acc[0][6] = fmaf(a0, w1.z, acc[0][6]);
    acc[0][7] = fmaf(a0, w1.w, acc[0][7]);
    acc[1][0] = fmaf(a1, w0.x, acc[1][0]);
    acc[1][1] = fmaf(a1, w0.y, acc[1][1]);
    acc[1][2] = fmaf(a1, w0.z, acc[1][2]);
    acc[1][3] = fmaf(a1, w0.w, acc[1][3]);
    acc[1][4] = fmaf(a1, w1.x, acc[1][4]);
    acc[1][5] = fmaf(a1, w1.y, acc[1][5]);
    acc[1][6] = fmaf(a1, w1.z, acc[1][6]);
    acc[1][7] = fmaf(a1, w1.w, acc[1][7]);
  }

  int grow0 = row0 + ty * 2;
#pragma unroll
  for (int r = 0; r < 2; ++r) {
    int grow = grow0 + r;
    if (grow < n) {
      float* op = out + (size_t)grow * CH + col0 + tx * 8;
#pragma unroll
      for (int j = 0; j < 8; ++j) {
        float v = acc[r][j];
        if (accum) v += op[j];
        if (bias) v += bias[col0 + tx * 8 + j];
        if (dorelu) v = fmaxf(v, 0.f);
        op[j] = v;
      }
    }
  }
}

// ---------------- GEMM: out[n x 16] (+)= in[n x 128] @ W[128 x 16]

__global__ __launch_bounds__(256) void k_gemm16(
    const float* __restrict__ in, const float* __restrict__ W,
    const float* __restrict__ bias, float* __restrict__ out,
    int n, int accum) {
  __shared__ float As[64 * 132];
  __shared__ float Ws[128 * 16];
  int t = threadIdx.x;
  int row0 = blockIdx.x * 64;

  for (int i = t; i < 128 * 4; i += 256) {   // float4 index
    int c = i >> 2;
    int j4 = i & 3;
    *reinterpret_cast<float4*>(&Ws[c * 16 + j4 * 4]) =
        *reinterpret_cast<const float4*>(&W[c * 16 + j4 * 4]);
  }
  for (int i = t; i < 64 * 32; i += 256) {
    int r = i >> 5;
    int c4 = i & 31;
    int grow = row0 + r;
    float4 a;
    if (grow < n) a = *reinterpret_cast<const float4*>(&in[(size_t)grow * CH + c4 * 4]);
    else { a.x = a.y = a.z = a.w = 0.f; }
    *reinterpret_cast<float4*>(&As[r * 132 + c4 * 4]) = a;
  }
  __syncthreads();

  int tx = t & 3;    // 4 col groups of 4
  int ty = t >> 2;   // 64 rows
  float acc[4] = {0.f, 0.f, 0.f, 0.f};
#pragma unroll 4
  for (int c = 0; c < 128; ++c) {
    float a = As[ty * 132 + c];
    const float4 w = *reinterpret_cast<const float4*>(&Ws[c * 16 + tx * 4]);
    acc[0] = fmaf(a, w.x, acc[0]);
    acc[1] = fmaf(a, w.y, acc[1]);
    acc[2] = fmaf(a, w.z, acc[2]);
    acc[3] = fmaf(a, w.w, acc[3]);
  }
  int grow = row0 + ty;
  if (grow < n) {
    float* op = out + (size_t)grow * CO + tx * 4;
#pragma unroll
    for (int j = 0; j < 4; ++j) {
      float v = acc[j];
      if (accum) v += op[j];
      if (bias) v += bias[tx * 4 + j];
      op[j] = v;
    }
  }
}

// ---------------- pooling + log_softmax ----------------

__global__ __launch_bounds__(256) void k_pool(
    const float* __restrict__ h, const int* __restrict__ batch,
    float* __restrict__ sums, float* __restrict__ cnts, int n) {
  __shared__ float sacc[NG * CO];
  __shared__ float scnt[NG];
  for (int i = threadIdx.x; i < NG * CO; i += 256) sacc[i] = 0.f;
  if (threadIdx.x < NG) scnt[threadIdx.x] = 0.f;
  __syncthreads();
  int ch = threadIdx.x & 15;
  int nl = threadIdx.x >> 4;   // 0..15
  int base = blockIdx.x * 1024;
  for (int i = 0; i < 64; ++i) {
    int node = base + i * 16 + nl;
    if (node < n) {
      int g = batch[node];
      atomicAdd(&sacc[g * CO + ch], h[(size_t)node * CO + ch]);
      if (ch == 0) atomicAdd(&scnt[g], 1.f);
    }
  }
  __syncthreads();
  for (int i = threadIdx.x; i < NG * CO; i += 256)
    if (sacc[i] != 0.f) atomicAdd(&sums[i], sacc[i]);
  if (threadIdx.x < NG && scnt[threadIdx.x] != 0.f)
    atomicAdd(&cnts[threadIdx.x], scnt[threadIdx.x]);
}

__global__ void k_lsm(const float* __restrict__ sums, const float* __restrict__ cnts,
                      float* __restrict__ out) {
  int g = threadIdx.x;
  if (g >= NG) return;
  float cnt = fmaxf(cnts[g], 1.f);
  float v[CO];
  float m = -1e30f;
#pragma unroll
  for (int c = 0; c < CO; ++c) { v[c] = sums[g * CO + c] / cnt; m = fmaxf(m, v[c]); }
  float s = 0.f;
#pragma unroll
  for (int c = 0; c < CO; ++c) s += expf(v[c] - m);
  float lse = m + logf(s);
#pragma unroll
  for (int c = 0; c < CO; ++c) out[g * CO + c] = v[c] - lse;
}

// ---------------- host ----------------

static void cheb_layer128(const float* in, const float* W, const float* b,
                          float* out, float* A, float* B, float* C,
                          const int* row_ptr, const int* ssrc, const float* sw,
                          int relu, hipStream_t stream) {
  dim3 gg((NN + 63) / 64, 2);
  dim3 gp((NN + 3) / 4);
  const int CC = CH * CH;
  k_gemm128<<<gg, 256, 0, stream>>>(in, W + 0 * CC, nullptr, out, NN, 0, 0);
  k_prop<<<gp, 256, 0, stream>>>(in, nullptr, A, row_ptr, ssrc, sw, NN);
  k_gemm128<<<gg, 256, 0, stream>>>(A, W + 1 * CC, nullptr, out, NN, 1, 0);
  k_prop<<<gp, 256, 0, stream>>>(A, in, B, row_ptr, ssrc, sw, NN);
  k_gemm128<<<gg, 256, 0, stream>>>(B, W + 2 * CC, nullptr, out, NN, 1, 0);
  k_prop<<<gp, 256, 0, stream>>>(B, A, C, row_ptr, ssrc, sw, NN);
  k_gemm128<<<gg, 256, 0, stream>>>(C, W + 3 * CC, nullptr, out, NN, 1, 0);
  k_prop<<<gp, 256, 0, stream>>>(C, B, A, row_ptr, ssrc, sw, NN);
  k_gemm128<<<gg, 256, 0, stream>>>(A, W + 4 * CC, b, out, NN, 1, relu);
}

extern "C" void kernel_launch(void* const* d_in, const int* in_sizes, int n_in,
                              void* d_out, int out_size, void* d_ws, size_t ws_size,
                              hipStream_t stream) {
  const float* x   = (const float*)d_in[0];
  const int* src   = (const int*)d_in[1];
  const int* dst   = (const int*)d_in[2];
  const int* batch = (const int*)d_in[3];
  const float* W1  = (const float*)d_in[4];
  const float* b1  = (const float*)d_in[5];
  const float* W2  = (const float*)d_in[6];
  const float* b2  = (const float*)d_in[7];
  const float* W3  = (const float*)d_in[8];
  const float* b3  = (const float*)d_in[9];
  float* out = (float*)d_out;

  char* p = (char*)d_ws;
  auto alloc = [&](size_t bytes) -> void* {
    void* r = (void*)p;
    p += (bytes + 511) & ~(size_t)511;
    return r;
  };
  int* deg     = (int*)alloc((size_t)NN * 4);
  int* hist    = (int*)alloc((size_t)NN * 4);
  int* fill    = (int*)alloc((size_t)NN * 4);
  int* row_ptr = (int*)alloc((size_t)(NN + 1) * 4);
  int* ssrc    = (int*)alloc((size_t)NE * 4);
  float* sw    = (float*)alloc((size_t)NE * 4);
  float* A  = (float*)alloc((size_t)NN * CH * 4);
  float* B  = (float*)alloc((size_t)NN * CH * 4);
  float* C  = (float*)alloc((size_t)NN * CH * 4);
  float* O1 = (float*)alloc((size_t)NN * CH * 4);
  float* O2 = (float*)alloc((size_t)NN * CH * 4);
  float* H3 = (float*)alloc((size_t)NN * CO * 4);
  float* pooled = (float*)alloc((size_t)NG * CO * 4);
  float* cnts   = (float*)alloc((size_t)NG * 4);

  hipMemsetAsync(deg, 0, (size_t)NN * 4, stream);
  hipMemsetAsync(hist, 0, (size_t)NN * 4, stream);
  hipMemsetAsync(fill, 0, (size_t)NN * 4, stream);
  hipMemsetAsync(pooled, 0, (size_t)NG * CO * 4, stream);
  hipMemsetAsync(cnts, 0, (size_t)NG * 4, stream);

  int egrid = (NE + 255) / 256;
  k_hist<<<egrid, 256, 0, stream>>>(src, dst, deg, hist, NE);
  k_scan<<<1, 1024, 0, stream>>>(hist, row_ptr, NN);
  k_scatter<<<egrid, 256, 0, stream>>>(src, dst, deg, row_ptr, fill, ssrc, sw, NE);

  // layer 1: x -> O1 (relu)
  cheb_layer128(x, W1, b1, O1, A, B, C, row_ptr, ssrc, sw, 1, stream);
  // layer 2: O1 -> O2 (relu)
  cheb_layer128(O1, W2, b2, O2, A, B, C, row_ptr, ssrc, sw, 1, stream);

  // layer 3: O2 -> H3 (16 cols, bias, no relu)
  {
    dim3 gg((NN + 63) / 64);
    dim3 gp((NN + 3) / 4);
    const int CC = CH * CO;
    k_gemm16<<<gg, 256, 0, stream>>>(O2, W3 + 0 * CC, nullptr, H3, NN, 0);
    k_prop<<<gp, 256, 0, stream>>>(O2, nullptr, A, row_ptr, ssrc, sw, NN);
    k_gemm16<<<gg, 256, 0, stream>>>(A, W3 + 1 * CC, nullptr, H3, NN, 1);
    k_prop<<<gp, 256, 0, stream>>>(A, O2, B, row_ptr, ssrc, sw, NN);
    k_gemm16<<<gg, 256, 0, stream>>>(B, W3 + 2 * CC, nullptr, H3, NN, 1);
    k_prop<<<gp, 256, 0, stream>>>(B, A, C, row_ptr, ssrc, sw, NN);
    k_gemm16<<<gg, 256, 0, stream>>>(C, W3 + 3 * CC, nullptr, H3, NN, 1);
    k_prop<<<gp, 256, 0, stream>>>(C, B, A, row_ptr, ssrc, sw, NN);
    k_gemm16<<<gg, 256, 0, stream>>>(A, W3 + 4 * CC, b3, H3, NN, 1);
  }

  // pool + log_softmax
  int pgrid = (NN + 1023) / 1024;
  k_pool<<<pgrid, 256, 0, stream>>>(H3, batch, pooled, cnts, NN);
  k_lsm<<<1, 64, 0, stream>>>(pooled, cnts, out);
}

// Round 2
// 888.393 us; speedup vs baseline: 2.1930x; 2.1930x over previous
//
#include <hip/hip_runtime.h>
#include <stdint.h>

#define NN 50000
#define NE 800000
#define NG 64
#define CH 128
#define CO 16
#define KH 640   // 5 * 128

typedef __attribute__((ext_vector_type(8))) short bf16x8;
typedef __attribute__((ext_vector_type(4))) float f32x4;

__device__ __forceinline__ ushort f2bf(float f) {
  uint32_t u = __float_as_uint(f);
  u += 0x7fffu + ((u >> 16) & 1u);
  return (ushort)(u >> 16);
}
__device__ __forceinline__ float bflo(uint32_t v) { return __uint_as_float(v << 16); }
__device__ __forceinline__ float bfhi(uint32_t v) { return __uint_as_float(v & 0xffff0000u); }

// ---------------- graph preprocessing ----------------

__global__ void k_hist(const int* __restrict__ src, const int* __restrict__ dst,
                       int* __restrict__ deg, int* __restrict__ hist, int E) {
  int e = blockIdx.x * blockDim.x + threadIdx.x;
  if (e < E) {
    atomicAdd(&deg[src[e]], 1);
    atomicAdd(&hist[dst[e]], 1);
  }
}

__global__ __launch_bounds__(1024) void k_scan_a(const int* __restrict__ hist,
                                                 int* __restrict__ row_ptr,
                                                 int* __restrict__ bsum, int n) {
  __shared__ int sm[1024];
  int i = blockIdx.x * 1024 + threadIdx.x;
  int v = (i < n) ? hist[i] : 0;
  sm[threadIdx.x] = v;
  __syncthreads();
  for (int off = 1; off < 1024; off <<= 1) {
    int t = (threadIdx.x >= off) ? sm[threadIdx.x - off] : 0;
    __syncthreads();
    sm[threadIdx.x] += t;
    __syncthreads();
  }
  if (i < n) row_ptr[i + 1] = sm[threadIdx.x];
  if (threadIdx.x == 1023) bsum[blockIdx.x] = sm[1023];
}

__global__ void k_scan_b(int* __restrict__ bsum, int nb) {
  if (threadIdx.x == 0) {
    int off = 0;
    for (int i = 0; i < nb; ++i) { int t = bsum[i]; bsum[i] = off; off += t; }
  }
}

__global__ __launch_bounds__(1024) void k_scan_c(const int* __restrict__ bsum,
                                                 int* __restrict__ row_ptr, int n) {
  int i = blockIdx.x * 1024 + threadIdx.x;
  if (i == 0) row_ptr[0] = 0;
  if (i < n) row_ptr[i + 1] += bsum[blockIdx.x];
}

__global__ void k_scatter(const int* __restrict__ src, const int* __restrict__ dst,
                          const int* __restrict__ deg, const int* __restrict__ row_ptr,
                          int* __restrict__ fill, int2* __restrict__ esw, int E) {
  int e = blockIdx.x * blockDim.x + threadIdx.x;
  if (e < E) {
    int s = src[e], d = dst[e];
    int ds = deg[s], dd = deg[d];
    float di = ds > 0 ? rsqrtf((float)ds) : 0.f;
    float dj = dd > 0 ? rsqrtf((float)dd) : 0.f;
    float w = -di * dj;
    int pos = row_ptr[d] + atomicAdd(&fill[d], 1);
    int2 p; p.x = s; p.y = __float_as_int(w);
    esw[pos] = p;
  }
}

// ---------------- conversions ----------------

// x [NN][128] f32 -> slice0 of buf (row stride KH), bf16
__global__ __launch_bounds__(256) void k_cvt_x(const float* __restrict__ x,
                                               ushort* __restrict__ buf) {
  int t = blockIdx.x * 256 + threadIdx.x;       // over NN*64 float2's
  if (t >= NN * 64) return;
  int node = t >> 6, p = t & 63;
  float2 v = reinterpret_cast<const float2*>(x)[t];
  uint32_t w = (uint32_t)f2bf(v.x) | ((uint32_t)f2bf(v.y) << 16);
  *reinterpret_cast<uint32_t*>(buf + (size_t)node * KH + p * 2) = w;
}

// W [640][cout] f32 -> Wt [cout][640] bf16
__global__ __launch_bounds__(256) void k_cvt_w(const float* __restrict__ W,
                                               ushort* __restrict__ Wt, int cout) {
  int t = blockIdx.x * 256 + threadIdx.x;       // over 640*cout
  if (t >= KH * cout) return;
  int kc = t / cout, nc = t - kc * cout;
  Wt[(size_t)nc * KH + kc] = f2bf(W[t]);
}

// ---------------- propagation (bf16): out[i] = sum w_e * h[src_e], opt 2*p - tx0

__global__ __launch_bounds__(256) void k_prop_bf(
    const ushort* __restrict__ hin, const ushort* __restrict__ tx0,
    ushort* __restrict__ hout, const int* __restrict__ row_ptr,
    const int2* __restrict__ esw, int n) {
  int wave = threadIdx.x >> 6;
  int lane = threadIdx.x & 63;
  int node = blockIdx.x * 4 + wave;
  if (node >= n) return;
  int beg = row_ptr[node], end = row_ptr[node + 1];
  float ax = 0.f, ay = 0.f;
  int co = lane * 2;
  int e = beg;
  for (; e + 2 <= end; e += 2) {
    int2 p0 = esw[e], p1 = esw[e + 1];
    float w0 = __int_as_float(p0.y), w1 = __int_as_float(p1.y);
    uint32_t v0 = *reinterpret_cast<const uint32_t*>(hin + (size_t)p0.x * KH + co);
    uint32_t v1 = *reinterpret_cast<const uint32_t*>(hin + (size_t)p1.x * KH + co);
    ax = fmaf(w0, bflo(v0), ax);
    ay = fmaf(w0, bfhi(v0), ay);
    ax = fmaf(w1, bflo(v1), ax);
    ay = fmaf(w1, bfhi(v1), ay);
  }
  if (e < end) {
    int2 p0 = esw[e];
    float w0 = __int_as_float(p0.y);
    uint32_t v0 = *reinterpret_cast<const uint32_t*>(hin + (size_t)p0.x * KH + co);
    ax = fmaf(w0, bflo(v0), ax);
    ay = fmaf(w0, bfhi(v0), ay);
  }
  size_t o = (size_t)node * KH + co;
  if (tx0) {
    uint32_t t0 = *reinterpret_cast<const uint32_t*>(tx0 + o);
    ax = 2.f * ax - bflo(t0);
    ay = 2.f * ay - bfhi(t0);
  }
  uint32_t w = (uint32_t)f2bf(ax) | ((uint32_t)f2bf(ay) << 16);
  *reinterpret_cast<uint32_t*>(hout + o) = w;
}

// ---------------- MFMA GEMM: out[n x 128] = A[n x 640] @ W[640 x 128] ----------------
// A bf16 row-major stride KH; Wt bf16 [128][640] (W transposed); out bf16 slice
// (row stride KH) with bias (+relu).

__global__ __launch_bounds__(256) void k_gemm_mfma128(
    const ushort* __restrict__ A, const ushort* __restrict__ Wt,
    const float* __restrict__ bias, ushort* __restrict__ outbf,
    int n, int dorelu) {
  int wave = threadIdx.x >> 6, lane = threadIdx.x & 63;
  int rowbase = blockIdx.x * 128 + wave * 32;
  int lr = lane & 15, lk = (lane >> 4) * 8;

  f32x4 acc[2][8];
#pragma unroll
  for (int r = 0; r < 2; ++r)
#pragma unroll
    for (int c = 0; c < 8; ++c) acc[r][c] = (f32x4){0.f, 0.f, 0.f, 0.f};

  int r0 = min(rowbase + lr, n - 1);
  int r1 = min(rowbase + 16 + lr, n - 1);
  const ushort* pa0 = A + (size_t)r0 * KH + lk;
  const ushort* pa1 = A + (size_t)r1 * KH + lk;
  const ushort* pb = Wt + (size_t)lr * KH + lk;

  for (int k0 = 0; k0 < KH; k0 += 32) {
    bf16x8 a0 = *reinterpret_cast<const bf16x8*>(pa0 + k0);
    bf16x8 a1 = *reinterpret_cast<const bf16x8*>(pa1 + k0);
#pragma unroll
    for (int c = 0; c < 8; ++c) {
      bf16x8 b = *reinterpret_cast<const bf16x8*>(pb + (size_t)c * 16 * KH + k0);
      acc[0][c] = __builtin_amdgcn_mfma_f32_16x16x32_bf16(a0, b, acc[0][c], 0, 0, 0);
      acc[1][c] = __builtin_amdgcn_mfma_f32_16x16x32_bf16(a1, b, acc[1][c], 0, 0, 0);
    }
  }

#pragma unroll
  for (int r = 0; r < 2; ++r) {
#pragma unroll
    for (int c = 0; c < 8; ++c) {
      int col = c * 16 + lr;
      float bs = bias[col];
#pragma unroll
      for (int i = 0; i < 4; ++i) {
        int row = rowbase + r * 16 + (lane >> 4) * 4 + i;
        if (row < n) {
          float v = acc[r][c][i] + bs;
          if (dorelu) v = fmaxf(v, 0.f);
          outbf[(size_t)row * KH + col] = f2bf(v);
        }
      }
    }
  }
}

// out[n x 16] f32 = A[n x 640] @ W[640 x 16] + bias
__global__ __launch_bounds__(256) void k_gemm_mfma16(
    const ushort* __restrict__ A, const ushort* __restrict__ Wt,
    const float* __restrict__ bias, float* __restrict__ out, int n) {
  int wave = threadIdx.x >> 6, lane = threadIdx.x & 63;
  int rowbase = blockIdx.x * 256 + wave * 64;
  int lr = lane & 15, lk = (lane >> 4) * 8;

  f32x4 acc[4];
#pragma unroll
  for (int r = 0; r < 4; ++r) acc[r] = (f32x4){0.f, 0.f, 0.f, 0.f};

  const ushort* pa[4];
#pragma unroll
  for (int r = 0; r < 4; ++r) {
    int rr = min(rowbase + r * 16 + lr, n - 1);
    pa[r] = A + (size_t)rr * KH + lk;
  }
  const ushort* pb = Wt + (size_t)lr * KH + lk;

  for (int k0 = 0; k0 < KH; k0 += 32) {
    bf16x8 b = *reinterpret_cast<const bf16x8*>(pb + k0);
#pragma unroll
    for (int r = 0; r < 4; ++r) {
      bf16x8 a = *reinterpret_cast<const bf16x8*>(pa[r] + k0);
      acc[r] = __builtin_amdgcn_mfma_f32_16x16x32_bf16(a, b, acc[r], 0, 0, 0);
    }
  }

  float bs = bias[lr];
#pragma unroll
  for (int r = 0; r < 4; ++r) {
#pragma unroll
    for (int i = 0; i < 4; ++i) {
      int row = rowbase + r * 16 + (lane >> 4) * 4 + i;
      if (row < n) out[(size_t)row * CO + lr] = acc[r][i] + bs;
    }
  }
}

// ---------------- pooling + log_softmax ----------------

__global__ __launch_bounds__(256) void k_pool(
    const float* __restrict__ h, const int* __restrict__ batch,
    float* __restrict__ sums, float* __restrict__ cnts, int n) {
  __shared__ float sacc[NG * CO];
  __shared__ float scnt[NG];
  for (int i = threadIdx.x; i < NG * CO; i += 256) sacc[i] = 0.f;
  if (threadIdx.x < NG) scnt[threadIdx.x] = 0.f;
  __syncthreads();
  int ch = threadIdx.x & 15;
  int nl = threadIdx.x >> 4;
  int base = blockIdx.x * 1024;
  for (int i = 0; i < 64; ++i) {
    int node = base + i * 16 + nl;
    if (node < n) {
      int g = batch[node];
      atomicAdd(&sacc[g * CO + ch], h[(size_t)node * CO + ch]);
      if (ch == 0) atomicAdd(&scnt[g], 1.f);
    }
  }
  __syncthreads();
  for (int i = threadIdx.x; i < NG * CO; i += 256)
    if (sacc[i] != 0.f) atomicAdd(&sums[i], sacc[i]);
  if (threadIdx.x < NG && scnt[threadIdx.x] != 0.f)
    atomicAdd(&cnts[threadIdx.x], scnt[threadIdx.x]);
}

__global__ void k_lsm(const float* __restrict__ sums, const float* __restrict__ cnts,
                      float* __restrict__ out) {
  int g = threadIdx.x;
  if (g >= NG) return;
  float cnt = fmaxf(cnts[g], 1.f);
  float v[CO];
  float m = -1e30f;
#pragma unroll
  for (int c = 0; c < CO; ++c) { v[c] = sums[g * CO + c] / cnt; m = fmaxf(m, v[c]); }
  float s = 0.f;
#pragma unroll
  for (int c = 0; c < CO; ++c) s += expf(v[c] - m);
  float lse = m + logf(s);
#pragma unroll
  for (int c = 0; c < CO; ++c) out[g * CO + c] = v[c] - lse;
}

// ---------------- host ----------------

static void run_props(ushort* buf, const int* row_ptr, const int2* esw,
                      hipStream_t stream) {
  dim3 gp((NN + 3) / 4);
  // slices: element (node,s,c) at buf[node*KH + s*128 + c]
  k_prop_bf<<<gp, 256, 0, stream>>>(buf + 0 * CH, nullptr,   buf + 1 * CH, row_ptr, esw, NN);
  k_prop_bf<<<gp, 256, 0, stream>>>(buf + 1 * CH, buf + 0 * CH, buf + 2 * CH, row_ptr, esw, NN);
  k_prop_bf<<<gp, 256, 0, stream>>>(buf + 2 * CH, buf + 1 * CH, buf + 3 * CH, row_ptr, esw, NN);
  k_prop_bf<<<gp, 256, 0, stream>>>(buf + 3 * CH, buf + 2 * CH, buf + 4 * CH, row_ptr, esw, NN);
}

extern "C" void kernel_launch(void* const* d_in, const int* in_sizes, int n_in,
                              void* d_out, int out_size, void* d_ws, size_t ws_size,
                              hipStream_t stream) {
  const float* x   = (const float*)d_in[0];
  const int* src   = (const int*)d_in[1];
  const int* dst   = (const int*)d_in[2];
  const int* batch = (const int*)d_in[3];
  const float* W1  = (const float*)d_in[4];
  const float* b1  = (const float*)d_in[5];
  const float* W2  = (const float*)d_in[6];
  const float* b2  = (const float*)d_in[7];
  const float* W3  = (const float*)d_in[8];
  const float* b3  = (const float*)d_in[9];
  float* out = (float*)d_out;

  char* p = (char*)d_ws;
  auto alloc = [&](size_t bytes) -> void* {
    void* r = (void*)p;
    p += (bytes + 511) & ~(size_t)511;
    return r;
  };
  int* deg     = (int*)alloc((size_t)NN * 4);
  int* hist    = (int*)alloc((size_t)NN * 4);
  int* fill    = (int*)alloc((size_t)NN * 4);
  int* row_ptr = (int*)alloc((size_t)(NN + 1) * 4);
  int* bsum    = (int*)alloc(64 * 4);
  int2* esw    = (int2*)alloc((size_t)NE * 8);
  ushort* bufA = (ushort*)alloc((size_t)NN * KH * 2);
  ushort* bufB = (ushort*)alloc((size_t)NN * KH * 2);
  ushort* Wt1  = (ushort*)alloc((size_t)CH * KH * 2);
  ushort* Wt2  = (ushort*)alloc((size_t)CH * KH * 2);
  ushort* Wt3  = (ushort*)alloc((size_t)CO * KH * 2);
  float* pooled = (float*)alloc((size_t)NG * CO * 4);
  float* cnts   = (float*)alloc((size_t)NG * 4);
  float* H3 = (float*)bufB;   // alias: bufB free by the time H3 is produced

  hipMemsetAsync(deg, 0, (size_t)NN * 4, stream);
  hipMemsetAsync(hist, 0, (size_t)NN * 4, stream);
  hipMemsetAsync(fill, 0, (size_t)NN * 4, stream);
  hipMemsetAsync(pooled, 0, (size_t)NG * CO * 4, stream);
  hipMemsetAsync(cnts, 0, (size_t)NG * 4, stream);

  int egrid = (NE + 255) / 256;
  int nsb = (NN + 1023) / 1024;  // 49
  k_hist<<<egrid, 256, 0, stream>>>(src, dst, deg, hist, NE);
  k_scan_a<<<nsb, 1024, 0, stream>>>(hist, row_ptr, bsum, NN);
  k_scan_b<<<1, 64, 0, stream>>>(bsum, nsb);
  k_scan_c<<<nsb, 1024, 0, stream>>>(bsum, row_ptr, NN);
  k_scatter<<<egrid, 256, 0, stream>>>(src, dst, deg, row_ptr, fill, esw, NE);

  k_cvt_x<<<(NN * 64 + 255) / 256, 256, 0, stream>>>(x, bufA);
  k_cvt_w<<<(KH * CH + 255) / 256, 256, 0, stream>>>(W1, Wt1, CH);
  k_cvt_w<<<(KH * CH + 255) / 256, 256, 0, stream>>>(W2, Wt2, CH);
  k_cvt_w<<<(KH * CO + 255) / 256, 256, 0, stream>>>(W3, Wt3, CO);

  dim3 gg128((NN + 127) / 128);
  dim3 gg16((NN + 255) / 256);

  // layer 1: bufA slices -> bufB slice0 (relu)
  run_props(bufA, row_ptr, esw, stream);
  k_gemm_mfma128<<<gg128, 256, 0, stream>>>(bufA, Wt1, b1, bufB, NN, 1);

  // layer 2: bufB slices -> bufA slice0 (relu)
  run_props(bufB, row_ptr, esw, stream);
  k_gemm_mfma128<<<gg128, 256, 0, stream>>>(bufB, Wt2, b2, bufA, NN, 1);

  // layer 3: bufA slices -> H3 (fp32, bias, no relu)
  run_props(bufA, row_ptr, esw, stream);
  k_gemm_mfma16<<<gg16, 256, 0, stream>>>(bufA, Wt3, b3, H3, NN);

  // pool + log_softmax
  int pgrid = (NN + 1023) / 1024;
  k_pool<<<pgrid, 256, 0, stream>>>(H3, batch, pooled, cnts, NN);
  k_lsm<<<1, 64, 0, stream>>>(pooled, cnts, out);
}

// Round 3
// 680.211 us; speedup vs baseline: 2.8642x; 1.3061x over previous
//
#include <hip/hip_runtime.h>
#include <stdint.h>

#define NN 50000
#define NE 800000
#define NG 64
#define CH 128
#define CO 16
#define KH 640   // 5 * 128

typedef __attribute__((ext_vector_type(8))) short bf16x8;
typedef __attribute__((ext_vector_type(4))) float f32x4;

__device__ __forceinline__ ushort f2bf(float f) {
  uint32_t u = __float_as_uint(f);
  u += 0x7fffu + ((u >> 16) & 1u);
  return (ushort)(u >> 16);
}
__device__ __forceinline__ float bflo(uint32_t v) { return __uint_as_float(v << 16); }
__device__ __forceinline__ float bfhi(uint32_t v) { return __uint_as_float(v & 0xffff0000u); }

// ---------------- graph preprocessing ----------------

__global__ void k_hist(const int* __restrict__ src, const int* __restrict__ dst,
                       int* __restrict__ deg, int* __restrict__ hist, int E) {
  int e = blockIdx.x * blockDim.x + threadIdx.x;
  if (e < E) {
    atomicAdd(&deg[src[e]], 1);
    atomicAdd(&hist[dst[e]], 1);
  }
}

__global__ __launch_bounds__(1024) void k_scan_a(const int* __restrict__ hist,
                                                 int* __restrict__ row_ptr,
                                                 int* __restrict__ bsum, int n) {
  __shared__ int sm[1024];
  int i = blockIdx.x * 1024 + threadIdx.x;
  int v = (i < n) ? hist[i] : 0;
  sm[threadIdx.x] = v;
  __syncthreads();
  for (int off = 1; off < 1024; off <<= 1) {
    int t = (threadIdx.x >= off) ? sm[threadIdx.x - off] : 0;
    __syncthreads();
    sm[threadIdx.x] += t;
    __syncthreads();
  }
  if (i < n) row_ptr[i + 1] = sm[threadIdx.x];
  if (threadIdx.x == 1023) bsum[blockIdx.x] = sm[1023];
}

__global__ void k_scan_b(int* __restrict__ bsum, int nb) {
  if (threadIdx.x == 0) {
    int off = 0;
    for (int i = 0; i < nb; ++i) { int t = bsum[i]; bsum[i] = off; off += t; }
  }
}

__global__ __launch_bounds__(1024) void k_scan_c(const int* __restrict__ bsum,
                                                 int* __restrict__ row_ptr, int n) {
  int i = blockIdx.x * 1024 + threadIdx.x;
  if (i == 0) row_ptr[0] = 0;
  if (i < n) row_ptr[i + 1] += bsum[blockIdx.x];
}

__global__ void k_scatter(const int* __restrict__ src, const int* __restrict__ dst,
                          const int* __restrict__ deg, const int* __restrict__ row_ptr,
                          int* __restrict__ fill, int2* __restrict__ esw, int E) {
  int e = blockIdx.x * blockDim.x + threadIdx.x;
  if (e < E) {
    int s = src[e], d = dst[e];
    int ds = deg[s], dd = deg[d];
    float di = ds > 0 ? rsqrtf((float)ds) : 0.f;
    float dj = dd > 0 ? rsqrtf((float)dd) : 0.f;
    float w = -di * dj;
    int pos = row_ptr[d] + atomicAdd(&fill[d], 1);
    int2 p; p.x = s; p.y = __float_as_int(w);
    esw[pos] = p;
  }
}

// ---------------- conversions ----------------

__global__ __launch_bounds__(256) void k_cvt_x(const float* __restrict__ x,
                                               ushort* __restrict__ buf) {
  int t = blockIdx.x * 256 + threadIdx.x;       // over NN*64 float2's
  if (t >= NN * 64) return;
  int node = t >> 6, p = t & 63;
  float2 v = reinterpret_cast<const float2*>(x)[t];
  uint32_t w = (uint32_t)f2bf(v.x) | ((uint32_t)f2bf(v.y) << 16);
  *reinterpret_cast<uint32_t*>(buf + (size_t)node * KH + p * 2) = w;
}

// W [640][cout] f32 -> Wt [cout][640] bf16
__global__ __launch_bounds__(256) void k_cvt_w(const float* __restrict__ W,
                                               ushort* __restrict__ Wt, int cout) {
  int t = blockIdx.x * 256 + threadIdx.x;
  if (t >= KH * cout) return;
  int kc = t / cout, nc = t - kc * cout;
  Wt[(size_t)nc * KH + kc] = f2bf(W[t]);
}

// W3 [5][128][16] f32 -> Wt3v [80][128] bf16 : Wt3v[k*16+j][c] = W3[k][c][j]
__global__ __launch_bounds__(256) void k_cvt_w3(const float* __restrict__ W,
                                                ushort* __restrict__ Wt) {
  int t = blockIdx.x * 256 + threadIdx.x;
  if (t >= 5 * CH * CO) return;
  int k = t / (CH * CO);
  int r = t - k * CH * CO;
  int c = r / CO, j = r - c * CO;
  Wt[(size_t)(k * CO + j) * CH + c] = f2bf(W[t]);
}

// ---------------- propagation (bf16, 128 ch): out = 2*L(hin) - tx0 (or L(hin))

__global__ __launch_bounds__(256) void k_prop_bf(
    const ushort* __restrict__ hin, const ushort* __restrict__ tx0,
    ushort* __restrict__ hout, const int* __restrict__ row_ptr,
    const int2* __restrict__ esw, int n) {
  int wave = threadIdx.x >> 6;
  int lane = threadIdx.x & 63;
  int node = blockIdx.x * 4 + wave;
  if (node >= n) return;
  int beg = row_ptr[node], end = row_ptr[node + 1];
  float ax = 0.f, ay = 0.f;
  int co = lane * 2;
  const ushort* hc = hin + co;
  int e = beg;
  for (; e + 4 <= end; e += 4) {
    int2 p0 = esw[e], p1 = esw[e + 1], p2 = esw[e + 2], p3 = esw[e + 3];
    uint32_t v0 = *reinterpret_cast<const uint32_t*>(hc + (size_t)p0.x * KH);
    uint32_t v1 = *reinterpret_cast<const uint32_t*>(hc + (size_t)p1.x * KH);
    uint32_t v2 = *reinterpret_cast<const uint32_t*>(hc + (size_t)p2.x * KH);
    uint32_t v3 = *reinterpret_cast<const uint32_t*>(hc + (size_t)p3.x * KH);
    float w0 = __int_as_float(p0.y), w1 = __int_as_float(p1.y);
    float w2 = __int_as_float(p2.y), w3 = __int_as_float(p3.y);
    ax = fmaf(w0, bflo(v0), ax);
    ay = fmaf(w0, bfhi(v0), ay);
    ax = fmaf(w1, bflo(v1), ax);
    ay = fmaf(w1, bfhi(v1), ay);
    ax = fmaf(w2, bflo(v2), ax);
    ay = fmaf(w2, bfhi(v2), ay);
    ax = fmaf(w3, bflo(v3), ax);
    ay = fmaf(w3, bfhi(v3), ay);
  }
  for (; e < end; ++e) {
    int2 p0 = esw[e];
    float w0 = __int_as_float(p0.y);
    uint32_t v0 = *reinterpret_cast<const uint32_t*>(hc + (size_t)p0.x * KH);
    ax = fmaf(w0, bflo(v0), ax);
    ay = fmaf(w0, bfhi(v0), ay);
  }
  size_t o = (size_t)node * KH + co;
  if (tx0) {
    uint32_t t0 = *reinterpret_cast<const uint32_t*>(tx0 + o);
    ax = 2.f * ax - bflo(t0);
    ay = 2.f * ay - bfhi(t0);
  }
  uint32_t w = (uint32_t)f2bf(ax) | ((uint32_t)f2bf(ay) << 16);
  *reinterpret_cast<uint32_t*>(hout + o) = w;
}

// ---------------- propagation (bf16, 16 ch) with Clenshaw combine ----------------
// r = scale*L(gin) - prev + v  [+ bias -> f32 out]

__global__ __launch_bounds__(256) void k_prop16(
    const ushort* __restrict__ gin, int gstride,
    const ushort* __restrict__ prev, int pstride,
    const ushort* __restrict__ v, int vstride,
    const float* __restrict__ bias,
    ushort* __restrict__ bout, float* __restrict__ fout,
    float scale, const int* __restrict__ row_ptr,
    const int2* __restrict__ esw, int n) {
  int wave = threadIdx.x >> 6;
  int lane = threadIdx.x & 63;
  int node = blockIdx.x * 4 + wave;
  if (node >= n) return;
  int beg = row_ptr[node], end = row_ptr[node + 1];
  int ch2 = lane & 7;       // uint index over 16 channels
  int grp = lane >> 3;      // 8 edge subgroups
  float ax = 0.f, ay = 0.f;
  const ushort* gc = gin + ch2 * 2;
  for (int e = beg + grp; e < end; e += 8) {
    int2 p = esw[e];
    float w = __int_as_float(p.y);
    uint32_t vv = *reinterpret_cast<const uint32_t*>(gc + (size_t)p.x * gstride);
    ax = fmaf(w, bflo(vv), ax);
    ay = fmaf(w, bfhi(vv), ay);
  }
#pragma unroll
  for (int off = 8; off < 64; off <<= 1) {
    ax += __shfl_xor(ax, off, 64);
    ay += __shfl_xor(ay, off, 64);
  }
  if (lane < 8) {
    float rx = scale * ax, ry = scale * ay;
    if (prev) {
      uint32_t pv = *reinterpret_cast<const uint32_t*>(prev + (size_t)node * pstride + lane * 2);
      rx -= bflo(pv);
      ry -= bfhi(pv);
    }
    uint32_t vv = *reinterpret_cast<const uint32_t*>(v + (size_t)node * vstride + lane * 2);
    rx += bflo(vv);
    ry += bfhi(vv);
    if (fout) {
      fout[(size_t)node * CO + lane * 2]     = rx + bias[lane * 2];
      fout[(size_t)node * CO + lane * 2 + 1] = ry + bias[lane * 2 + 1];
    } else {
      uint32_t w = (uint32_t)f2bf(rx) | ((uint32_t)f2bf(ry) << 16);
      *reinterpret_cast<uint32_t*>(bout + (size_t)node * CO + lane * 2) = w;
    }
  }
}

// ---------------- MFMA GEMM: out slice = A[n x 640] @ W[640 x 128] + bias, relu

__global__ __launch_bounds__(256) void k_gemm_mfma128(
    const ushort* __restrict__ A, const ushort* __restrict__ Wt,
    const float* __restrict__ bias, ushort* __restrict__ outbf,
    int n, int dorelu) {
  int wave = threadIdx.x >> 6, lane = threadIdx.x & 63;
  int rowbase = blockIdx.x * 128 + wave * 32;
  int lr = lane & 15, lk = (lane >> 4) * 8;

  f32x4 acc[2][8];
#pragma unroll
  for (int r = 0; r < 2; ++r)
#pragma unroll
    for (int c = 0; c < 8; ++c) acc[r][c] = (f32x4){0.f, 0.f, 0.f, 0.f};

  int r0 = min(rowbase + lr, n - 1);
  int r1 = min(rowbase + 16 + lr, n - 1);
  const ushort* pa0 = A + (size_t)r0 * KH + lk;
  const ushort* pa1 = A + (size_t)r1 * KH + lk;
  const ushort* pb = Wt + (size_t)lr * KH + lk;

  for (int k0 = 0; k0 < KH; k0 += 32) {
    bf16x8 a0 = *reinterpret_cast<const bf16x8*>(pa0 + k0);
    bf16x8 a1 = *reinterpret_cast<const bf16x8*>(pa1 + k0);
#pragma unroll
    for (int c = 0; c < 8; ++c) {
      bf16x8 b = *reinterpret_cast<const bf16x8*>(pb + (size_t)c * 16 * KH + k0);
      acc[0][c] = __builtin_amdgcn_mfma_f32_16x16x32_bf16(a0, b, acc[0][c], 0, 0, 0);
      acc[1][c] = __builtin_amdgcn_mfma_f32_16x16x32_bf16(a1, b, acc[1][c], 0, 0, 0);
    }
  }

#pragma unroll
  for (int r = 0; r < 2; ++r) {
#pragma unroll
    for (int c = 0; c < 8; ++c) {
      int col = c * 16 + lr;
      float bs = bias[col];
#pragma unroll
      for (int i = 0; i < 4; ++i) {
        int row = rowbase + r * 16 + (lane >> 4) * 4 + i;
        if (row < n) {
          float v = acc[r][c][i] + bs;
          if (dorelu) v = fmaxf(v, 0.f);
          outbf[(size_t)row * KH + col] = f2bf(v);
        }
      }
    }
  }
}

// V[n x 80] bf16 = A[n x 128] @ Wt3v^T  (Wt3v [80][128])
__global__ __launch_bounds__(256) void k_gemm_v(
    const ushort* __restrict__ A, const ushort* __restrict__ Wt,
    ushort* __restrict__ V, int n) {
  int wave = threadIdx.x >> 6, lane = threadIdx.x & 63;
  int rowbase = blockIdx.x * 256 + wave * 64;
  int lr = lane & 15, lk = (lane >> 4) * 8;

  f32x4 acc[4][5];
#pragma unroll
  for (int r = 0; r < 4; ++r)
#pragma unroll
    for (int c = 0; c < 5; ++c) acc[r][c] = (f32x4){0.f, 0.f, 0.f, 0.f};

  const ushort* pa[4];
#pragma unroll
  for (int r = 0; r < 4; ++r) {
    int rr = min(rowbase + r * 16 + lr, n - 1);
    pa[r] = A + (size_t)rr * KH + lk;
  }
  const ushort* pb = Wt + (size_t)lr * CH + lk;

  for (int k0 = 0; k0 < CH; k0 += 32) {
    bf16x8 a[4];
#pragma unroll
    for (int r = 0; r < 4; ++r) a[r] = *reinterpret_cast<const bf16x8*>(pa[r] + k0);
#pragma unroll
    for (int c = 0; c < 5; ++c) {
      bf16x8 b = *reinterpret_cast<const bf16x8*>(pb + (size_t)c * 16 * CH + k0);
#pragma unroll
      for (int r = 0; r < 4; ++r)
        acc[r][c] = __builtin_amdgcn_mfma_f32_16x16x32_bf16(a[r], b, acc[r][c], 0, 0, 0);
    }
  }

#pragma unroll
  for (int r = 0; r < 4; ++r) {
#pragma unroll
    for (int c = 0; c < 5; ++c) {
      int col = c * 16 + lr;
#pragma unroll
      for (int i = 0; i < 4; ++i) {
        int row = rowbase + r * 16 + (lane >> 4) * 4 + i;
        if (row < n) V[(size_t)row * 80 + col] = f2bf(acc[r][c][i]);
      }
    }
  }
}

// ---------------- pooling + log_softmax ----------------

__global__ __launch_bounds__(256) void k_pool(
    const float* __restrict__ h, const int* __restrict__ batch,
    float* __restrict__ sums, float* __restrict__ cnts, int n) {
  __shared__ float sacc[NG * CO];
  __shared__ float scnt[NG];
  for (int i = threadIdx.x; i < NG * CO; i += 256) sacc[i] = 0.f;
  if (threadIdx.x < NG) scnt[threadIdx.x] = 0.f;
  __syncthreads();
  int ch = threadIdx.x & 15;
  int nl = threadIdx.x >> 4;
  int base = blockIdx.x * 1024;
  for (int i = 0; i < 64; ++i) {
    int node = base + i * 16 + nl;
    if (node < n) {
      int g = batch[node];
      atomicAdd(&sacc[g * CO + ch], h[(size_t)node * CO + ch]);
      if (ch == 0) atomicAdd(&scnt[g], 1.f);
    }
  }
  __syncthreads();
  for (int i = threadIdx.x; i < NG * CO; i += 256)
    if (sacc[i] != 0.f) atomicAdd(&sums[i], sacc[i]);
  if (threadIdx.x < NG && scnt[threadIdx.x] != 0.f)
    atomicAdd(&cnts[threadIdx.x], scnt[threadIdx.x]);
}

__global__ void k_lsm(const float* __restrict__ sums, const float* __restrict__ cnts,
                      float* __restrict__ out) {
  int g = threadIdx.x;
  if (g >= NG) return;
  float cnt = fmaxf(cnts[g], 1.f);
  float v[CO];
  float m = -1e30f;
#pragma unroll
  for (int c = 0; c < CO; ++c) { v[c] = sums[g * CO + c] / cnt; m = fmaxf(m, v[c]); }
  float s = 0.f;
#pragma unroll
  for (int c = 0; c < CO; ++c) s += expf(v[c] - m);
  float lse = m + logf(s);
#pragma unroll
  for (int c = 0; c < CO; ++c) out[g * CO + c] = v[c] - lse;
}

// ---------------- host ----------------

static void run_props(ushort* buf, const int* row_ptr, const int2* esw,
                      hipStream_t stream) {
  dim3 gp((NN + 3) / 4);
  k_prop_bf<<<gp, 256, 0, stream>>>(buf + 0 * CH, nullptr,      buf + 1 * CH, row_ptr, esw, NN);
  k_prop_bf<<<gp, 256, 0, stream>>>(buf + 1 * CH, buf + 0 * CH, buf + 2 * CH, row_ptr, esw, NN);
  k_prop_bf<<<gp, 256, 0, stream>>>(buf + 2 * CH, buf + 1 * CH, buf + 3 * CH, row_ptr, esw, NN);
  k_prop_bf<<<gp, 256, 0, stream>>>(buf + 3 * CH, buf + 2 * CH, buf + 4 * CH, row_ptr, esw, NN);
}

extern "C" void kernel_launch(void* const* d_in, const int* in_sizes, int n_in,
                              void* d_out, int out_size, void* d_ws, size_t ws_size,
                              hipStream_t stream) {
  const float* x   = (const float*)d_in[0];
  const int* src   = (const int*)d_in[1];
  const int* dst   = (const int*)d_in[2];
  const int* batch = (const int*)d_in[3];
  const float* W1  = (const float*)d_in[4];
  const float* b1  = (const float*)d_in[5];
  const float* W2  = (const float*)d_in[6];
  const float* b2  = (const float*)d_in[7];
  const float* W3  = (const float*)d_in[8];
  const float* b3  = (const float*)d_in[9];
  float* out = (float*)d_out;

  char* p = (char*)d_ws;
  auto alloc = [&](size_t bytes) -> void* {
    void* r = (void*)p;
    p += (bytes + 511) & ~(size_t)511;
    return r;
  };
  int* deg     = (int*)alloc((size_t)NN * 4);
  int* hist    = (int*)alloc((size_t)NN * 4);
  int* fill    = (int*)alloc((size_t)NN * 4);
  int* row_ptr = (int*)alloc((size_t)(NN + 1) * 4);
  int* bsum    = (int*)alloc(64 * 4);
  int2* esw    = (int2*)alloc((size_t)NE * 8);
  ushort* bufA = (ushort*)alloc((size_t)NN * KH * 2);
  ushort* bufB = (ushort*)alloc((size_t)NN * KH * 2);
  ushort* Wt1  = (ushort*)alloc((size_t)CH * KH * 2);
  ushort* Wt2  = (ushort*)alloc((size_t)CH * KH * 2);
  ushort* Wt3v = (ushort*)alloc((size_t)80 * CH * 2);
  float* pooled = (float*)alloc((size_t)NG * CO * 4);
  float* cnts   = (float*)alloc((size_t)NG * 4);

  // layer-3 scratch aliases into bufB (free after layer-2 GEMM consumes it)
  ushort* V   = bufB;                       // [NN][80] bf16
  ushort* bb3 = bufB + (size_t)NN * 80;     // [NN][16] bf16
  ushort* bb2 = bb3 + (size_t)NN * CO;
  ushort* bb1 = bb2 + (size_t)NN * CO;
  float*  H3  = (float*)(bb1 + (size_t)NN * CO);  // [NN][16] f32

  hipMemsetAsync(deg, 0, (size_t)NN * 4, stream);
  hipMemsetAsync(hist, 0, (size_t)NN * 4, stream);
  hipMemsetAsync(fill, 0, (size_t)NN * 4, stream);
  hipMemsetAsync(pooled, 0, (size_t)NG * CO * 4, stream);
  hipMemsetAsync(cnts, 0, (size_t)NG * 4, stream);

  int egrid = (NE + 255) / 256;
  int nsb = (NN + 1023) / 1024;
  k_hist<<<egrid, 256, 0, stream>>>(src, dst, deg, hist, NE);
  k_scan_a<<<nsb, 1024, 0, stream>>>(hist, row_ptr, bsum, NN);
  k_scan_b<<<1, 64, 0, stream>>>(bsum, nsb);
  k_scan_c<<<nsb, 1024, 0, stream>>>(bsum, row_ptr, NN);
  k_scatter<<<egrid, 256, 0, stream>>>(src, dst, deg, row_ptr, fill, esw, NE);

  k_cvt_x<<<(NN * 64 + 255) / 256, 256, 0, stream>>>(x, bufA);
  k_cvt_w<<<(KH * CH + 255) / 256, 256, 0, stream>>>(W1, Wt1, CH);
  k_cvt_w<<<(KH * CH + 255) / 256, 256, 0, stream>>>(W2, Wt2, CH);
  k_cvt_w3<<<(5 * CH * CO + 255) / 256, 256, 0, stream>>>(W3, Wt3v);

  dim3 gg128((NN + 127) / 128);
  dim3 gg256((NN + 255) / 256);
  dim3 gp4((NN + 3) / 4);

  // layer 1: bufA slices -> bufB slice0 (relu)
  run_props(bufA, row_ptr, esw, stream);
  k_gemm_mfma128<<<gg128, 256, 0, stream>>>(bufA, Wt1, b1, bufB, NN, 1);

  // layer 2: bufB slices -> bufA slice0 (relu)
  run_props(bufB, row_ptr, esw, stream);
  k_gemm_mfma128<<<gg128, 256, 0, stream>>>(bufB, Wt2, b2, bufA, NN, 1);

  // layer 3 via Clenshaw: V = h2 @ W3cat; b_k = 2L b_{k+1} - b_{k+2} + v_k
  k_gemm_v<<<gg256, 256, 0, stream>>>(bufA, Wt3v, V, NN);
  k_prop16<<<gp4, 256, 0, stream>>>(V + 64, 80, nullptr, 0, V + 48, 80, nullptr,
                                    bb3, nullptr, 2.f, row_ptr, esw, NN);
  k_prop16<<<gp4, 256, 0, stream>>>(bb3, CO, V + 64, 80, V + 32, 80, nullptr,
                                    bb2, nullptr, 2.f, row_ptr, esw, NN);
  k_prop16<<<gp4, 256, 0, stream>>>(bb2, CO, bb3, CO, V + 16, 80, nullptr,
                                    bb1, nullptr, 2.f, row_ptr, esw, NN);
  k_prop16<<<gp4, 256, 0, stream>>>(bb1, CO, bb2, CO, V + 0, 80, b3,
                                    nullptr, H3, 1.f, row_ptr, esw, NN);

  // pool + log_softmax
  int pgrid = (NN + 1023) / 1024;
  k_pool<<<pgrid, 256, 0, stream>>>(H3, batch, pooled, cnts, NN);
  k_lsm<<<1, 64, 0, stream>>>(pooled, cnts, out);
}